// Round 3
// baseline (8155.746 us; speedup 1.0000x reference)
//
#include <hip/hip_runtime.h>
#include <stdint.h>

// PAM_Module: B=8, C=512, H=W=64 -> N=4096, O=64. Dtype auto-detected (bf16 vs fp32).
// out = gamma * (vw @ (xf @ att^T) + vb) + x   (softmax rows sum to 1 => vb passes through)
// ws layout (16B-aligned):
//   flag @0 | gf @16 | bcat @32 (512B) | vbf @544 (2048B) | wt @2592 (512x128 f32)
//   vwf @264736 (512x512 f32) | Qd @1313312 (B*N*64 f32) | Kd @9701920 (B*N*64 f32)
//   total 18,090,528 B

#define B_ 8
#define C_ 512
#define N_ 4096

typedef unsigned short u16;
typedef unsigned int u32;

__device__ __forceinline__ float b2f(u16 u) {
    return __uint_as_float(((u32)u) << 16);
}
__device__ __forceinline__ u16 f2b(float f) {
    u32 u = __float_as_uint(f);
    u = u + 0x7fffu + ((u >> 16) & 1u);   // RNE
    return (u16)(u >> 16);
}
// load element i of a float array that is either bf16 (fl=1) or fp32 (fl=0)
__device__ __forceinline__ float ldf(const void* p, int i, int fl) {
    return fl ? b2f(((const u16*)p)[i]) : ((const float*)p)[i];
}

// ---------------- kernel 0: dtype detector ----------------------------------------
__global__ void detect_dtype(const u16* __restrict__ x, int* __restrict__ flag) {
    __shared__ int cnt[256];
    int t = threadIdx.x;
    int c = 0;
    for (int i = t; i < 4096; i += 256) {
        int e = (x[i] >> 7) & 0xFF;
        if (e >= 95 && e <= 140) c++;
    }
    cnt[t] = c;
    __syncthreads();
    for (int s = 128; s > 0; s >>= 1) {
        if (t < s) cnt[t] += cnt[t + s];
        __syncthreads();
    }
    if (t == 0) *flag = (cnt[0] >= 3686) ? 1 : 0;   // 1 = bf16, 0 = fp32
}

// ---------------- kernel 1: params -> fp32 ws -------------------------------------
__global__ void prep_params(const void* __restrict__ qw, const void* __restrict__ qb,
                            const void* __restrict__ kw, const void* __restrict__ kb,
                            const void* __restrict__ vw, const void* __restrict__ vb,
                            const void* __restrict__ gm, const int* __restrict__ flagp,
                            float* __restrict__ wt, float* __restrict__ bcat,
                            float* __restrict__ vwf, float* __restrict__ vbf,
                            float* __restrict__ gf) {
    int fl = *flagp;
    int gid = blockIdx.x * 256 + threadIdx.x;   // grid 1024*256 = 262144
    if (gid < C_ * C_) vwf[gid] = ldf(vw, gid, fl);
    if (gid < C_ * 128) {
        int c = gid >> 7, o = gid & 127;
        wt[c * 128 + o] = (o < 64) ? ldf(qw, o * C_ + c, fl)
                                   : ldf(kw, (o - 64) * C_ + c, fl);
    }
    if (gid < 128) bcat[gid] = (gid < 64) ? ldf(qb, gid, fl) : ldf(kb, gid - 64, fl);
    if (gid < C_) vbf[gid] = ldf(vb, gid, fl);
    if (gid == 0) gf[0] = ldf(gm, 0, fl);
}

// ---------------- kernel 2: Q/K projection, grid (2, 64, 8) -----------------------
__global__ __launch_bounds__(256) void proj_qk(
        const void* __restrict__ xin, const int* __restrict__ flagp,
        const float* __restrict__ wt, const float* __restrict__ bcat,
        float* __restrict__ Qd, float* __restrict__ Kd) {
    __shared__ __align__(16) char smem[32768];
    float* xs  = (float*)smem;            // [64][64]
    float* wsh = (float*)(smem + 16384);  // [64][64]
    const u16*   xb = (const u16*)xin;
    const float* xf = (const float*)xin;
    int fl = *flagp;

    int t = threadIdx.x;
    int og = blockIdx.x;
    int n0 = blockIdx.y * 64;
    int b  = blockIdx.z;
    int oc0 = og * 64;
    int tn = t & 15, to = t >> 4;

    float acc[4][4];
#pragma unroll
    for (int i = 0; i < 4; ++i)
#pragma unroll
        for (int j = 0; j < 4; ++j) acc[i][j] = 0.f;

    for (int c0 = 0; c0 < C_; c0 += 64) {
        __syncthreads();
        if (fl) {
#pragma unroll
            for (int rep = 0; rep < 4; ++rep) {
                int idx4 = rep * 256 + t;
                int cc = idx4 >> 4;
                int nn4 = (idx4 & 15) << 2;
                ushort4 uv = *(const ushort4*)(xb + ((size_t)(b * C_ + c0 + cc)) * N_ + n0 + nn4);
                float4 f;
                f.x = b2f(uv.x); f.y = b2f(uv.y); f.z = b2f(uv.z); f.w = b2f(uv.w);
                *(float4*)(xs + cc * 64 + nn4) = f;
            }
        } else {
#pragma unroll
            for (int rep = 0; rep < 4; ++rep) {
                int idx4 = rep * 256 + t;
                int cc = idx4 >> 4;
                int nn4 = (idx4 & 15) << 2;
                *(float4*)(xs + cc * 64 + nn4) =
                    *(const float4*)(xf + ((size_t)(b * C_ + c0 + cc)) * N_ + n0 + nn4);
            }
        }
#pragma unroll
        for (int rep = 0; rep < 4; ++rep) {
            int idx4 = rep * 256 + t;
            int cc = idx4 >> 4;
            int oo4 = (idx4 & 15) << 2;
            *(float4*)(wsh + cc * 64 + oo4) =
                *(const float4*)(wt + (size_t)(c0 + cc) * 128 + oc0 + oo4);
        }
        __syncthreads();
#pragma unroll 8
        for (int cc = 0; cc < 64; ++cc) {
            float4 xa = *(const float4*)(xs + cc * 64 + (tn << 2));
            float4 wa = *(const float4*)(wsh + cc * 64 + (to << 2));
            acc[0][0] += xa.x * wa.x; acc[0][1] += xa.x * wa.y;
            acc[0][2] += xa.x * wa.z; acc[0][3] += xa.x * wa.w;
            acc[1][0] += xa.y * wa.x; acc[1][1] += xa.y * wa.y;
            acc[1][2] += xa.y * wa.z; acc[1][3] += xa.y * wa.w;
            acc[2][0] += xa.z * wa.x; acc[2][1] += xa.z * wa.y;
            acc[2][2] += xa.z * wa.z; acc[2][3] += xa.z * wa.w;
            acc[3][0] += xa.w * wa.x; acc[3][1] += xa.w * wa.y;
            acc[3][2] += xa.w * wa.z; acc[3][3] += xa.w * wa.w;
        }
    }

    float b0 = bcat[oc0 + (to << 2) + 0];
    float b1 = bcat[oc0 + (to << 2) + 1];
    float b2 = bcat[oc0 + (to << 2) + 2];
    float b3 = bcat[oc0 + (to << 2) + 3];
    float* dst = (og == 0) ? Qd : Kd;
#pragma unroll
    for (int i = 0; i < 4; ++i) {
        int n = n0 + (tn << 2) + i;
        float4 o4 = make_float4(acc[i][0] + b0, acc[i][1] + b1,
                                acc[i][2] + b2, acc[i][3] + b3);
        *(float4*)(dst + ((size_t)b * N_ + n) * 64 + (to << 2)) = o4;
    }
}

// ---------------- kernel 3: flash attention + fused vw epilogue -------------------
#define OFF_QS   0        // qs  [16][68] f32   4352
#define OFF_KST  4352     // kst [64][33] f32   8448
#define OFF_PS   12800    // ps  [16][36] f32   2304
#define OFF_ALS  15104    // als [16] f32       64
#define OFF_LS   15168    // ls  [16] f32       64
#define OFF_XS   15232    // xs  [512][34] u16  34816 (overlaid by ys [16][520] f32)
#define SMEM_SZ  50048

__global__ __launch_bounds__(256) void attn_fused(
        const float* __restrict__ Qd, const float* __restrict__ Kd,
        const void* __restrict__ xin, const int* __restrict__ flagp,
        const float* __restrict__ vwf, const float* __restrict__ vbf,
        const float* __restrict__ gf, void* __restrict__ outv) {
    __shared__ __align__(16) char smem[SMEM_SZ];
    float* qsf  = (float*)(smem + OFF_QS);
    float* kstf = (float*)(smem + OFF_KST);
    float* psf  = (float*)(smem + OFF_PS);
    float* alsf = (float*)(smem + OFF_ALS);
    float* lsf  = (float*)(smem + OFF_LS);
    u16*   xsu  = (u16*)  (smem + OFF_XS);
    float* ysf  = (float*)(smem + OFF_XS);   // overlay after j-loop

    const u16*   xb = (const u16*)xin;
    const float* xf = (const float*)xin;
    int fl = *flagp;

    int t  = threadIdx.x;
    int b  = blockIdx.y;
    int i0 = blockIdx.x * 16;
    int jj = t & 31;
    int g  = t >> 5;
    int r0 = g * 2, r1 = r0 + 1;

    {   // Q tile (visible after iteration-0 second barrier)
        int r = t >> 4, c4 = (t & 15) << 2;
        *(float4*)(qsf + r * 68 + c4) =
            *(const float4*)(Qd + ((size_t)b * N_ + i0 + r) * 64 + c4);
    }

    float m0 = -1e30f, m1 = -1e30f, l0 = 0.f, l1 = 0.f;
    float oa[16][2];
#pragma unroll
    for (int r = 0; r < 16; ++r) { oa[r][0] = 0.f; oa[r][1] = 0.f; }

    for (int j0 = 0; j0 < N_; j0 += 32) {
        __syncthreads();
#pragma unroll
        for (int rep = 0; rep < 2; ++rep) {
            int idx4 = rep * 256 + t;
            int kr = idx4 >> 4;
            int c4 = (idx4 & 15) << 2;
            float4 k4 = *(const float4*)(Kd + ((size_t)b * N_ + j0 + kr) * 64 + c4);
            kstf[(c4 + 0) * 33 + kr] = k4.x;
            kstf[(c4 + 1) * 33 + kr] = k4.y;
            kstf[(c4 + 2) * 33 + kr] = k4.z;
            kstf[(c4 + 3) * 33 + kr] = k4.w;
        }
        if (fl) {
#pragma unroll
            for (int rep = 0; rep < 8; ++rep) {
                int idx = rep * 256 + t;
                int c = idx >> 2;
                int j8 = (idx & 3) << 3;
                uint4 v = *(const uint4*)(xb + ((size_t)(b * C_ + c)) * N_ + j0 + j8);
                u32* d = (u32*)(xsu + c * 34 + j8);
                d[0] = v.x; d[1] = v.y; d[2] = v.z; d[3] = v.w;
            }
        } else {
#pragma unroll
            for (int rep = 0; rep < 8; ++rep) {
                int idx = rep * 256 + t;
                int c = idx >> 2;
                int j8 = (idx & 3) << 3;
                const float* sp = xf + ((size_t)(b * C_ + c)) * N_ + j0 + j8;
                float4 fa = *(const float4*)(sp);
                float4 fb = *(const float4*)(sp + 4);
                u32* d = (u32*)(xsu + c * 34 + j8);
                d[0] = (u32)f2b(fa.x) | ((u32)f2b(fa.y) << 16);
                d[1] = (u32)f2b(fa.z) | ((u32)f2b(fa.w) << 16);
                d[2] = (u32)f2b(fb.x) | ((u32)f2b(fb.y) << 16);
                d[3] = (u32)f2b(fb.z) | ((u32)f2b(fb.w) << 16);
            }
        }
        __syncthreads();

        // ---- QK^T: rows r0,r1 x col jj ----
        float s0 = 0.f, s1 = 0.f;
#pragma unroll
        for (int c = 0; c < 64; c += 4) {
            float4 qa  = *(const float4*)(qsf + r0 * 68 + c);
            float4 qb4 = *(const float4*)(qsf + r1 * 68 + c);
            float k0 = kstf[(c + 0) * 33 + jj], k1 = kstf[(c + 1) * 33 + jj];
            float k2 = kstf[(c + 2) * 33 + jj], k3 = kstf[(c + 3) * 33 + jj];
            s0 += qa.x * k0 + qa.y * k1 + qa.z * k2 + qa.w * k3;
            s1 += qb4.x * k0 + qb4.y * k1 + qb4.z * k2 + qb4.w * k3;
        }
        float tm0 = s0, tm1 = s1;
#pragma unroll
        for (int off = 16; off > 0; off >>= 1) {
            tm0 = fmaxf(tm0, __shfl_xor(tm0, off, 64));
            tm1 = fmaxf(tm1, __shfl_xor(tm1, off, 64));
        }
        float mn0 = fmaxf(m0, tm0), mn1 = fmaxf(m1, tm1);
        float a0 = __expf(m0 - mn0), a1 = __expf(m1 - mn1);
        float p0 = __expf(s0 - mn0), p1 = __expf(s1 - mn1);
        float sum0 = p0, sum1 = p1;
#pragma unroll
        for (int off = 16; off > 0; off >>= 1) {
            sum0 += __shfl_xor(sum0, off, 64);
            sum1 += __shfl_xor(sum1, off, 64);
        }
        l0 = a0 * l0 + sum0; l1 = a1 * l1 + sum1;
        m0 = mn0; m1 = mn1;
        psf[r0 * 36 + jj] = p0;
        psf[r1 * 36 + jj] = p1;
        if (jj == 0) { alsf[r0] = a0; alsf[r1] = a1; }
        __syncthreads();

        // ---- y-accumulate over this key tile ----
#pragma unroll
        for (int r = 0; r < 16; ++r) {
            float a = alsf[r];
            oa[r][0] *= a; oa[r][1] *= a;
        }
        const u16* xr0 = xsu + t * 34;
        const u16* xr1 = xsu + (t + 256) * 34;
#pragma unroll 2
        for (int j = 0; j < 32; j += 4) {
            u32 a01 = *(const u32*)(xr0 + j);
            u32 a23 = *(const u32*)(xr0 + j + 2);
            u32 b01 = *(const u32*)(xr1 + j);
            u32 b23 = *(const u32*)(xr1 + j + 2);
            float v00 = __uint_as_float(a01 << 16);
            float v01 = __uint_as_float(a01 & 0xffff0000u);
            float v02 = __uint_as_float(a23 << 16);
            float v03 = __uint_as_float(a23 & 0xffff0000u);
            float v10 = __uint_as_float(b01 << 16);
            float v11 = __uint_as_float(b01 & 0xffff0000u);
            float v12 = __uint_as_float(b23 << 16);
            float v13 = __uint_as_float(b23 & 0xffff0000u);
#pragma unroll
            for (int r = 0; r < 16; ++r) {
                float4 pr = *(const float4*)(psf + r * 36 + j);
                oa[r][0] += pr.x * v00 + pr.y * v01 + pr.z * v02 + pr.w * v03;
                oa[r][1] += pr.x * v10 + pr.y * v11 + pr.z * v12 + pr.w * v13;
            }
        }
    }

    if (jj == 0) { lsf[r0] = l0; lsf[r1] = l1; }
    __syncthreads();   // ls visible; xs reads done before ys overlay

#pragma unroll
    for (int r = 0; r < 16; ++r) {
        float inv = 1.0f / lsf[r];
        ysf[r * 520 + t]       = oa[r][0] * inv;
        ysf[r * 520 + t + 256] = oa[r][1] * inv;
    }
    __syncthreads();

    // epilogue: out[c,i] = gamma * (vwf[c,:] @ y[:,i] + vbf[c]) + x[c,i]
    const float* vwr0 = vwf + (size_t)t * C_;
    const float* vwr1 = vwf + (size_t)(t + 256) * C_;
    float acc0[16], acc1[16];
#pragma unroll
    for (int i = 0; i < 16; ++i) { acc0[i] = 0.f; acc1[i] = 0.f; }

    for (int cb = 0; cb < C_; cb += 16) {
        float4 w00 = *(const float4*)(vwr0 + cb);
        float4 w01 = *(const float4*)(vwr0 + cb + 4);
        float4 w02 = *(const float4*)(vwr0 + cb + 8);
        float4 w03 = *(const float4*)(vwr0 + cb + 12);
        float4 w10 = *(const float4*)(vwr1 + cb);
        float4 w11 = *(const float4*)(vwr1 + cb + 4);
        float4 w12 = *(const float4*)(vwr1 + cb + 8);
        float4 w13 = *(const float4*)(vwr1 + cb + 12);
#pragma unroll
        for (int i = 0; i < 16; ++i) {
            const float* yrow = ysf + i * 520 + cb;
            float4 y0 = *(const float4*)(yrow + 0);
            float4 y1 = *(const float4*)(yrow + 4);
            float4 y2 = *(const float4*)(yrow + 8);
            float4 y3 = *(const float4*)(yrow + 12);
            acc0[i] += w00.x*y0.x + w00.y*y0.y + w00.z*y0.z + w00.w*y0.w
                     + w01.x*y1.x + w01.y*y1.y + w01.z*y1.z + w01.w*y1.w
                     + w02.x*y2.x + w02.y*y2.y + w02.z*y2.z + w02.w*y2.w
                     + w03.x*y3.x + w03.y*y3.y + w03.z*y3.z + w03.w*y3.w;
            acc1[i] += w10.x*y0.x + w10.y*y0.y + w10.z*y0.z + w10.w*y0.w
                     + w11.x*y1.x + w11.y*y1.y + w11.z*y1.z + w11.w*y1.w
                     + w12.x*y2.x + w12.y*y2.y + w12.z*y2.z + w12.w*y2.w
                     + w13.x*y3.x + w13.y*y3.y + w13.z*y3.z + w13.w*y3.w;
        }
    }

    float gma = gf[0];
    float vb0 = vbf[t];
    float vb1 = vbf[t + 256];
    if (fl) {
        u16* outb = (u16*)outv;
#pragma unroll
        for (int half = 0; half < 2; ++half) {
            int ch = t + half * 256;
            float vbh = half ? vb1 : vb0;
            const float* ac = half ? acc1 : acc0;
            const u16* xr = xb + ((size_t)(b * C_ + ch)) * N_ + i0;
            u16* orow = outb + ((size_t)(b * C_ + ch)) * N_ + i0;
            uint4 xa = *(const uint4*)(xr);
            uint4 xc = *(const uint4*)(xr + 8);
            u32 xw[8] = {xa.x, xa.y, xa.z, xa.w, xc.x, xc.y, xc.z, xc.w};
            u32 ow[8];
#pragma unroll
            for (int p = 0; p < 8; ++p) {
                float xe = __uint_as_float(xw[p] << 16);
                float xo = __uint_as_float(xw[p] & 0xffff0000u);
                u16 lo = f2b(gma * (ac[2 * p] + vbh) + xe);
                u16 hi = f2b(gma * (ac[2 * p + 1] + vbh) + xo);
                ow[p] = (u32)lo | ((u32)hi << 16);
            }
            *(uint4*)(orow)     = make_uint4(ow[0], ow[1], ow[2], ow[3]);
            *(uint4*)(orow + 8) = make_uint4(ow[4], ow[5], ow[6], ow[7]);
        }
    } else {
        float* outf = (float*)outv;
#pragma unroll
        for (int half = 0; half < 2; ++half) {
            int ch = t + half * 256;
            float vbh = half ? vb1 : vb0;
            const float* ac = half ? acc1 : acc0;
            const float* xr = xf + ((size_t)(b * C_ + ch)) * N_ + i0;
            float* orow = outf + ((size_t)(b * C_ + ch)) * N_ + i0;
#pragma unroll
            for (int q4 = 0; q4 < 4; ++q4) {
                float4 xv = *(const float4*)(xr + q4 * 4);
                float4 ov;
                ov.x = gma * (ac[q4 * 4 + 0] + vbh) + xv.x;
                ov.y = gma * (ac[q4 * 4 + 1] + vbh) + xv.y;
                ov.z = gma * (ac[q4 * 4 + 2] + vbh) + xv.z;
                ov.w = gma * (ac[q4 * 4 + 3] + vbh) + xv.w;
                *(float4*)(orow + q4 * 4) = ov;
            }
        }
    }
}

extern "C" void kernel_launch(void* const* d_in, const int* in_sizes, int n_in,
                              void* d_out, int out_size, void* d_ws, size_t ws_size,
                              hipStream_t stream) {
    const void* x  = d_in[0];
    const void* qw = d_in[1];
    const void* qb = d_in[2];
    const void* kw = d_in[3];
    const void* kb = d_in[4];
    const void* vw = d_in[5];
    const void* vb = d_in[6];
    const void* gm = d_in[7];

    char* ws = (char*)d_ws;
    int*   flag = (int*)(ws + 0);
    float* gf   = (float*)(ws + 16);
    float* bcat = (float*)(ws + 32);
    float* vbf  = (float*)(ws + 544);
    float* wt   = (float*)(ws + 2592);
    float* vwf  = (float*)(ws + 264736);
    float* Qd   = (float*)(ws + 1313312);
    float* Kd   = (float*)(ws + 9701920);   // total 18,090,528 B

    detect_dtype<<<dim3(1), dim3(256), 0, stream>>>((const u16*)x, flag);
    prep_params<<<dim3(1024), dim3(256), 0, stream>>>(
        qw, qb, kw, kb, vw, vb, gm, flag, wt, bcat, vwf, vbf, gf);
    proj_qk<<<dim3(2, 64, 8), dim3(256), 0, stream>>>(x, flag, wt, bcat, Qd, Kd);
    attn_fused<<<dim3(N_ / 16, B_), dim3(256), 0, stream>>>(
        Qd, Kd, x, flag, vwf, vbf, gf, d_out);
}

// Round 5
// 1929.351 us; speedup vs baseline: 4.2272x; 4.2272x over previous
//
#include <hip/hip_runtime.h>
#include <stdint.h>

// PAM_Module: B=8, C=512, H=W=64 -> N=4096, O=64. Dtype auto-detected (bf16 vs fp32).
// out = gamma * (vw @ (xf @ att^T) + vb) + x   (softmax rows sum to 1 => vb passes through)
// MFMA pipeline:
//   K0 detect, K1 prep (wt/bcat/vbf/gf fp32), K2 proj -> Qb,Kb bf16 [b][n][64],
//   K3 attn_mfma: 2-pass exact softmax + PV + fused vw-GEMM epilogue (mfma 16x16x32 bf16)
// ws: flag@0 gf@16 bcat@32 vbf@544 wt@2592 Qb@264736 Kb@4459040  (total 8,653,344 B)

#define B_ 8
#define C_ 512
#define N_ 4096

typedef unsigned short u16;
typedef unsigned int u32;
typedef __attribute__((ext_vector_type(8))) short bf16x8;
typedef __attribute__((ext_vector_type(4))) float f32x4;

static __device__ __forceinline__ float b2f(u16 u) {
    return __uint_as_float(((u32)u) << 16);
}
static __device__ __forceinline__ u16 f2b(float f) {
    u32 u = __float_as_uint(f);
    u = u + 0x7fffu + ((u >> 16) & 1u);   // RNE
    return (u16)(u >> 16);
}
static __device__ __forceinline__ float ldf(const void* p, size_t i, int fl) {
    return fl ? b2f(((const u16*)p)[i]) : ((const float*)p)[i];
}

// ---------------- kernel 0: dtype detector ----------------------------------------
__global__ void detect_dtype(const u16* __restrict__ x, int* __restrict__ flag) {
    __shared__ int cnt[256];
    int t = threadIdx.x;
    int c = 0;
    for (int i = t; i < 4096; i += 256) {
        int e = (x[i] >> 7) & 0xFF;
        if (e >= 95 && e <= 140) c++;
    }
    cnt[t] = c;
    __syncthreads();
    for (int s = 128; s > 0; s >>= 1) {
        if (t < s) cnt[t] += cnt[t + s];
        __syncthreads();
    }
    if (t == 0) *flag = (cnt[0] >= 3686) ? 1 : 0;   // 1 = bf16, 0 = fp32
}

// ---------------- kernel 1: params -> fp32 ws -------------------------------------
__global__ void prep_params(const void* __restrict__ qw, const void* __restrict__ qb,
                            const void* __restrict__ kw, const void* __restrict__ kb,
                            const void* __restrict__ vb, const void* __restrict__ gm,
                            const int* __restrict__ flagp,
                            float* __restrict__ wt, float* __restrict__ bcat,
                            float* __restrict__ vbf, float* __restrict__ gf) {
    int fl = *flagp;
    int gid = blockIdx.x * 256 + threadIdx.x;   // grid 256*256 = 65536
    if (gid < C_ * 128) {
        int c = gid >> 7, o = gid & 127;
        wt[c * 128 + o] = (o < 64) ? ldf(qw, (size_t)o * C_ + c, fl)
                                   : ldf(kw, (size_t)(o - 64) * C_ + c, fl);
    }
    if (gid < 128) bcat[gid] = (gid < 64) ? ldf(qb, gid, fl) : ldf(kb, gid - 64, fl);
    if (gid < C_) vbf[gid] = ldf(vb, gid, fl);
    if (gid == 0) gf[0] = ldf(gm, 0, fl);
}

// ---------------- kernel 2: Q/K projection -> bf16, grid (2, 64, 8) ---------------
__global__ __launch_bounds__(256) void proj_qk(
        const void* __restrict__ xin, const int* __restrict__ flagp,
        const float* __restrict__ wt, const float* __restrict__ bcat,
        u16* __restrict__ Qb, u16* __restrict__ Kb) {
    __shared__ __align__(16) char smem[32768];
    float* xs  = (float*)smem;            // [64][64]
    float* wsh = (float*)(smem + 16384);  // [64][64]
    const u16*   xb = (const u16*)xin;
    const float* xf = (const float*)xin;
    int fl = *flagp;

    int t = threadIdx.x;
    int og = blockIdx.x;
    int n0 = blockIdx.y * 64;
    int b  = blockIdx.z;
    int oc0 = og * 64;
    int tn = t & 15, to = t >> 4;

    float acc[4][4];
#pragma unroll
    for (int i = 0; i < 4; ++i)
#pragma unroll
        for (int j = 0; j < 4; ++j) acc[i][j] = 0.f;

    for (int c0 = 0; c0 < C_; c0 += 64) {
        __syncthreads();
        if (fl) {
#pragma unroll
            for (int rep = 0; rep < 4; ++rep) {
                int idx4 = rep * 256 + t;
                int cc = idx4 >> 4;
                int nn4 = (idx4 & 15) << 2;
                ushort4 uv = *(const ushort4*)(xb + ((size_t)(b * C_ + c0 + cc)) * N_ + n0 + nn4);
                float4 f;
                f.x = b2f(uv.x); f.y = b2f(uv.y); f.z = b2f(uv.z); f.w = b2f(uv.w);
                *(float4*)(xs + cc * 64 + nn4) = f;
            }
        } else {
#pragma unroll
            for (int rep = 0; rep < 4; ++rep) {
                int idx4 = rep * 256 + t;
                int cc = idx4 >> 4;
                int nn4 = (idx4 & 15) << 2;
                *(float4*)(xs + cc * 64 + nn4) =
                    *(const float4*)(xf + ((size_t)(b * C_ + c0 + cc)) * N_ + n0 + nn4);
            }
        }
#pragma unroll
        for (int rep = 0; rep < 4; ++rep) {
            int idx4 = rep * 256 + t;
            int cc = idx4 >> 4;
            int oo4 = (idx4 & 15) << 2;
            *(float4*)(wsh + cc * 64 + oo4) =
                *(const float4*)(wt + (size_t)(c0 + cc) * 128 + oc0 + oo4);
        }
        __syncthreads();
#pragma unroll 8
        for (int cc = 0; cc < 64; ++cc) {
            float4 xa = *(const float4*)(xs + cc * 64 + (tn << 2));
            float4 wa = *(const float4*)(wsh + cc * 64 + (to << 2));
            acc[0][0] += xa.x * wa.x; acc[0][1] += xa.x * wa.y;
            acc[0][2] += xa.x * wa.z; acc[0][3] += xa.x * wa.w;
            acc[1][0] += xa.y * wa.x; acc[1][1] += xa.y * wa.y;
            acc[1][2] += xa.y * wa.z; acc[1][3] += xa.y * wa.w;
            acc[2][0] += xa.z * wa.x; acc[2][1] += xa.z * wa.y;
            acc[2][2] += xa.z * wa.z; acc[2][3] += xa.z * wa.w;
            acc[3][0] += xa.w * wa.x; acc[3][1] += xa.w * wa.y;
            acc[3][2] += xa.w * wa.z; acc[3][3] += xa.w * wa.w;
        }
    }

    float b0 = bcat[oc0 + (to << 2) + 0];
    float b1 = bcat[oc0 + (to << 2) + 1];
    float b2 = bcat[oc0 + (to << 2) + 2];
    float b3 = bcat[oc0 + (to << 2) + 3];
    u16* dst = (og == 0) ? Qb : Kb;
#pragma unroll
    for (int i = 0; i < 4; ++i) {
        int n = n0 + (tn << 2) + i;
        ushort4 h;
        h.x = f2b(acc[i][0] + b0); h.y = f2b(acc[i][1] + b1);
        h.z = f2b(acc[i][2] + b2); h.w = f2b(acc[i][3] + b3);
        *(ushort4*)(dst + ((size_t)b * N_ + n) * 64 + (to << 2)) = h;
    }
}

// ---------------- kernel 3: MFMA flash attention + fused vw epilogue --------------
// grid (32, 8), 512 threads (8 waves). Wave w: S/softmax rows i = 16w..16w+15;
// PV c-slice [64w, 64w+64); epilogue z-slice c' = [64w, 64w+64).
// LDS (u16 units; strides in u16: Ks 72 (=144B), xs 40 (=80B), Ps 40, ys 72):
#define KS2_OFF 0        // Ks2 [32][72]   4608 B   (pass-2 K tile)
#define XS_OFF  4608     // xs  [512][40]  40960 B  (x value tile)
#define KS1_OFF 4608     // Ks1 [128][72]  18432 B  (pass-1 K tile, overlays xs)
#define PS_OFF  45568    // Ps  [128][40]  10240 B  (P round-trip)
#define YS_OFF  0        // ys  [64][72]   9216 B   (epilogue y chunk, overlays Ks2/xs)
#define SMEM3   55808

__global__ __launch_bounds__(512, 2) void attn_mfma(
        const u16* __restrict__ Qb, const u16* __restrict__ Kb,
        const void* __restrict__ xin, const int* __restrict__ flagp,
        const void* __restrict__ vwin, const float* __restrict__ vbf,
        const float* __restrict__ gf, void* __restrict__ outv) {
    __shared__ __align__(16) char smem[SMEM3];
    u16* Ks2 = (u16*)(smem + KS2_OFF);
    u16* xsu = (u16*)(smem + XS_OFF);
    u16* Ks1 = (u16*)(smem + KS1_OFF);
    u16* Ps  = (u16*)(smem + PS_OFF);
    u16* ys  = (u16*)(smem + YS_OFF);

    const u16*   xb = (const u16*)xin;
    const float* xf = (const float*)xin;
    const int fl = *flagp;

    const int t = threadIdx.x;
    const int wv = t >> 6;
    const int lane = t & 63;
    const int L = lane & 15;
    const int q = lane >> 4;
    const int b = blockIdx.y;
    const int i0 = blockIdx.x * 128;

    // Q fragments (A-operand) for this wave's 16 rows: A[m=L][k=8q+j]
    const u16* qp = Qb + ((size_t)b * N_ + i0 + wv * 16 + L) * 64;
    bf16x8 qf0 = *(const bf16x8*)(qp + 8 * q);
    bf16x8 qf1 = *(const bf16x8*)(qp + 32 + 8 * q);

    float m0[4], l0[4];
#pragma unroll
    for (int r = 0; r < 4; ++r) { m0[r] = -1e30f; l0[r] = 0.f; }

    // ---- pass 1: exact per-row max & sum, j-tiles of 128 ----
    for (int j0 = 0; j0 < N_; j0 += 128) {
        __syncthreads();
        {   // stage K 128x64 bf16 -> Ks1 (stride 72): 512 thr x 2 uint4 = 8192 u16
            int row = t >> 2, c8 = (t & 3) * 16;
            const u16* kp = Kb + ((size_t)b * N_ + j0 + row) * 64 + c8;
            uint4 v0 = *(const uint4*)(kp);
            uint4 v1 = *(const uint4*)(kp + 8);
            *(uint4*)(Ks1 + row * 72 + c8)     = v0;
            *(uint4*)(Ks1 + row * 72 + c8 + 8) = v1;
        }
        __syncthreads();
        f32x4 s[8];
#pragma unroll
        for (int nt = 0; nt < 8; ++nt) {
            const u16* kr = Ks1 + (16 * nt + L) * 72;
            bf16x8 k0 = *(const bf16x8*)(kr + 8 * q);
            bf16x8 k1 = *(const bf16x8*)(kr + 32 + 8 * q);
            f32x4 z = {0.f, 0.f, 0.f, 0.f};
            z = __builtin_amdgcn_mfma_f32_16x16x32_bf16(qf0, k0, z, 0, 0, 0);
            z = __builtin_amdgcn_mfma_f32_16x16x32_bf16(qf1, k1, z, 0, 0, 0);
            s[nt] = z;
        }
#pragma unroll
        for (int r = 0; r < 4; ++r) {
            float tm = s[0][r];
#pragma unroll
            for (int nt = 1; nt < 8; ++nt) tm = fmaxf(tm, s[nt][r]);
#pragma unroll
            for (int off = 8; off > 0; off >>= 1)
                tm = fmaxf(tm, __shfl_xor(tm, off, 64));
            float mn = fmaxf(m0[r], tm);
            float sum = 0.f;
#pragma unroll
            for (int nt = 0; nt < 8; ++nt) sum += __expf(s[nt][r] - mn);
#pragma unroll
            for (int off = 8; off > 0; off >>= 1)
                sum += __shfl_xor(sum, off, 64);
            l0[r] = l0[r] * __expf(m0[r] - mn) + sum;
            m0[r] = mn;
        }
    }
    float il[4];
#pragma unroll
    for (int r = 0; r < 4; ++r) il[r] = 1.0f / l0[r];

    // ---- pass 2: y[c][i] = sum_j x[c][j] * p[i][j], j-tiles of 32 ----
    f32x4 acc[4][8];
#pragma unroll
    for (int a = 0; a < 4; ++a)
#pragma unroll
        for (int nb = 0; nb < 8; ++nb) acc[a][nb] = (f32x4){0.f, 0.f, 0.f, 0.f};

    for (int j0 = 0; j0 < N_; j0 += 32) {
        __syncthreads();
        {   // stage K 32x64 -> Ks2 (stride 72): 32 rows x 16 thr x 4 u16
            int row = t >> 4, c4 = (t & 15) * 4;
            const u16* kp = Kb + ((size_t)b * N_ + j0 + row) * 64 + c4;
            u32 a0 = *(const u32*)kp, a1 = *(const u32*)(kp + 2);
            u32* d = (u32*)(Ks2 + row * 72 + c4);
            d[0] = a0; d[1] = a1;
        }
        // stage x 512x32 -> xs (stride 40); thread t owns channel row t
        if (fl) {
            const u16* xp = xb + ((size_t)(b * C_ + t)) * N_ + j0;
            uint4 v0 = *(const uint4*)(xp);
            uint4 v1 = *(const uint4*)(xp + 8);
            uint4 v2 = *(const uint4*)(xp + 16);
            uint4 v3 = *(const uint4*)(xp + 24);
            u16* d = xsu + t * 40;
            *(uint4*)(d)      = v0; *(uint4*)(d + 8)  = v1;
            *(uint4*)(d + 16) = v2; *(uint4*)(d + 24) = v3;
        } else {
            const float* xp = xf + ((size_t)(b * C_ + t)) * N_ + j0;
            u16* d = xsu + t * 40;
#pragma unroll
            for (int c8 = 0; c8 < 4; ++c8) {
                float4 fa = *(const float4*)(xp + c8 * 8);
                float4 fb = *(const float4*)(xp + c8 * 8 + 4);
                uint4 o;
                o.x = (u32)f2b(fa.x) | ((u32)f2b(fa.y) << 16);
                o.y = (u32)f2b(fa.z) | ((u32)f2b(fa.w) << 16);
                o.z = (u32)f2b(fb.x) | ((u32)f2b(fb.y) << 16);
                o.w = (u32)f2b(fb.z) | ((u32)f2b(fb.w) << 16);
                *(uint4*)(d + c8 * 8) = o;
            }
        }
        __syncthreads();

        // S for own 16 rows x 32 j (2 n-tiles)
        f32x4 s0 = {0.f, 0.f, 0.f, 0.f}, s1 = {0.f, 0.f, 0.f, 0.f};
        {
            const u16* kr0 = Ks2 + L * 72;
            const u16* kr1 = Ks2 + (16 + L) * 72;
            bf16x8 ka0 = *(const bf16x8*)(kr0 + 8 * q);
            bf16x8 ka1 = *(const bf16x8*)(kr0 + 32 + 8 * q);
            bf16x8 kb0 = *(const bf16x8*)(kr1 + 8 * q);
            bf16x8 kb1 = *(const bf16x8*)(kr1 + 32 + 8 * q);
            s0 = __builtin_amdgcn_mfma_f32_16x16x32_bf16(qf0, ka0, s0, 0, 0, 0);
            s0 = __builtin_amdgcn_mfma_f32_16x16x32_bf16(qf1, ka1, s0, 0, 0, 0);
            s1 = __builtin_amdgcn_mfma_f32_16x16x32_bf16(qf0, kb0, s1, 0, 0, 0);
            s1 = __builtin_amdgcn_mfma_f32_16x16x32_bf16(qf1, kb1, s1, 0, 0, 0);
        }
        // p = exp(S - m)/l -> Ps rows (C-layout row = 4q+r, col = L / 16+L)
#pragma unroll
        for (int r = 0; r < 4; ++r) {
            float p0 = __expf(s0[r] - m0[r]) * il[r];
            float p1 = __expf(s1[r] - m0[r]) * il[r];
            int row = 16 * wv + 4 * q + r;
            Ps[row * 40 + L]      = f2b(p0);
            Ps[row * 40 + 16 + L] = f2b(p1);
        }
        __syncthreads();

        // PV: wave's c-slice (4 m-tiles) x all 128 i (8 n-tiles), K=32
        bf16x8 pb[8];
#pragma unroll
        for (int nt = 0; nt < 8; ++nt)
            pb[nt] = *(const bf16x8*)(Ps + (16 * nt + L) * 40 + 8 * q);
#pragma unroll
        for (int mt = 0; mt < 4; ++mt) {
            bf16x8 af = *(const bf16x8*)(xsu + (64 * wv + 16 * mt + L) * 40 + 8 * q);
#pragma unroll
            for (int nt = 0; nt < 8; ++nt)
                acc[mt][nt] = __builtin_amdgcn_mfma_f32_16x16x32_bf16(
                    af, pb[nt], acc[mt][nt], 0, 0, 0);
        }
    }

    // ---- fused epilogue: z = vw @ y, out = gamma*(z+vb) + x ----
    const float gma = gf[0];
#pragma unroll 1
    for (int ih = 0; ih < 2; ++ih) {
        f32x4 z[4][4];
#pragma unroll
        for (int a = 0; a < 4; ++a)
#pragma unroll
            for (int nb = 0; nb < 4; ++nb) z[a][nb] = (f32x4){0.f, 0.f, 0.f, 0.f};

#pragma unroll 1
        for (int kc = 0; kc < 8; ++kc) {
            __syncthreads();
            if (wv == kc) {   // stage this wave's y (c-chunk kc) for i-half ih
#pragma unroll
                for (int mt = 0; mt < 4; ++mt)
#pragma unroll
                    for (int nn = 0; nn < 4; ++nn) {
                        f32x4 a = acc[mt][ih * 4 + nn];
#pragma unroll
                        for (int r = 0; r < 4; ++r)
                            ys[(16 * nn + L) * 72 + 16 * mt + 4 * q + r] = f2b(a[r]);
                    }
            }
            __syncthreads();
#pragma unroll
            for (int nn = 0; nn < 4; ++nn) {
                const u16* yr = ys + (16 * nn + L) * 72;
                bf16x8 yb0 = *(const bf16x8*)(yr + 8 * q);
                bf16x8 yb1 = *(const bf16x8*)(yr + 32 + 8 * q);
#pragma unroll
                for (int mtp = 0; mtp < 4; ++mtp) {
                    int crow = 64 * wv + 16 * mtp + L;
                    bf16x8 af0, af1;
                    if (fl) {
                        const u16* wp = (const u16*)vwin + (size_t)crow * C_ + kc * 64;
                        af0 = *(const bf16x8*)(wp + 8 * q);
                        af1 = *(const bf16x8*)(wp + 32 + 8 * q);
                    } else {
                        const float* wp = (const float*)vwin + (size_t)crow * C_ + kc * 64;
                        const float* p0w = wp + 8 * q;
                        const float* p1w = wp + 32 + 8 * q;
                        uint4 o0, o1;
                        o0.x = (u32)f2b(p0w[0]) | ((u32)f2b(p0w[1]) << 16);
                        o0.y = (u32)f2b(p0w[2]) | ((u32)f2b(p0w[3]) << 16);
                        o0.z = (u32)f2b(p0w[4]) | ((u32)f2b(p0w[5]) << 16);
                        o0.w = (u32)f2b(p0w[6]) | ((u32)f2b(p0w[7]) << 16);
                        o1.x = (u32)f2b(p1w[0]) | ((u32)f2b(p1w[1]) << 16);
                        o1.y = (u32)f2b(p1w[2]) | ((u32)f2b(p1w[3]) << 16);
                        o1.z = (u32)f2b(p1w[4]) | ((u32)f2b(p1w[5]) << 16);
                        o1.w = (u32)f2b(p1w[6]) | ((u32)f2b(p1w[7]) << 16);
                        af0 = *(bf16x8*)&o0;
                        af1 = *(bf16x8*)&o1;
                    }
                    z[mtp][nn] = __builtin_amdgcn_mfma_f32_16x16x32_bf16(
                        af0, yb0, z[mtp][nn], 0, 0, 0);
                    z[mtp][nn] = __builtin_amdgcn_mfma_f32_16x16x32_bf16(
                        af1, yb1, z[mtp][nn], 0, 0, 0);
                }
            }
        }
        // store this i-half
#pragma unroll
        for (int mtp = 0; mtp < 4; ++mtp)
#pragma unroll
            for (int nn = 0; nn < 4; ++nn)
#pragma unroll
                for (int r = 0; r < 4; ++r) {
                    int cp = 64 * wv + 16 * mtp + 4 * q + r;
                    int ii = i0 + ih * 64 + 16 * nn + L;
                    size_t oi = ((size_t)(b * C_ + cp)) * N_ + ii;
                    float val = gma * (z[mtp][nn][r] + vbf[cp]);
                    if (fl) ((u16*)outv)[oi] = f2b(val + b2f(xb[oi]));
                    else    ((float*)outv)[oi] = val + xf[oi];
                }
    }
}

extern "C" void kernel_launch(void* const* d_in, const int* in_sizes, int n_in,
                              void* d_out, int out_size, void* d_ws, size_t ws_size,
                              hipStream_t stream) {
    const void* x  = d_in[0];
    const void* qw = d_in[1];
    const void* qb = d_in[2];
    const void* kw = d_in[3];
    const void* kb = d_in[4];
    const void* vw = d_in[5];
    const void* vb = d_in[6];
    const void* gm = d_in[7];

    char* ws = (char*)d_ws;
    int*   flag = (int*)(ws + 0);
    float* gf   = (float*)(ws + 16);
    float* bcat = (float*)(ws + 32);
    float* vbf  = (float*)(ws + 544);
    float* wt   = (float*)(ws + 2592);
    u16*   Qb   = (u16*)(ws + 264736);
    u16*   Kb   = (u16*)(ws + 4459040);   // total ws use: 8,653,344 B

    detect_dtype<<<dim3(1), dim3(256), 0, stream>>>((const u16*)x, flag);
    prep_params<<<dim3(256), dim3(256), 0, stream>>>(
        qw, qb, kw, kb, vb, gm, flag, wt, bcat, vbf, gf);
    proj_qk<<<dim3(2, 64, 8), dim3(256), 0, stream>>>(x, flag, wt, bcat, Qb, Kb);
    attn_mfma<<<dim3(32, 8), dim3(512), 0, stream>>>(
        Qb, Kb, x, flag, vw, vbf, gf, d_out);
}